// Round 17
// baseline (136.922 us; speedup 1.0000x reference)
//
#include <hip/hip_runtime.h>

#define WF 512
#define HF 256
#define CF 64
#define NDTOT 65
#define DP 72            // padded d-stride in ws (f16), 144 B rows
#define APAD 36          // padded ch-stride (f16) of LDS col-major tiles

static constexpr size_t CH  = (size_t)HF * WF;
static constexpr size_t WH  = (size_t)HF * WF;
static constexpr float  INV = 1.0f / 576.0f;

typedef _Float16 f16;
typedef _Float16 f16x4 __attribute__((ext_vector_type(4)));
typedef _Float16 f16x8 __attribute__((ext_vector_type(8)));
typedef float    f32x4 __attribute__((ext_vector_type(4)));
typedef unsigned int u32x4 __attribute__((ext_vector_type(4)));

// ---------------------------------------------------------------------------
// k1 (R17): banded Gram via MFMA, single-f16 (validated R16), memory-system-
// oriented rebuild:
//  - strip = 256 cols, 256 thr, lane=column staging -> every global load is
//    ONE 1 KB contiguous burst (DRAM-friendly);
//  - B OOB zeroed at staging (no compute masks);
//  - ws written with nontemporal stores (streams past L3, protects the
//    268 MB inputs' L3 residency across graph replays);
//  - XCD swizzle: consecutive (b,y) rows + both strips on one XCD.
// Wave w owns 64 output cols: 4 x-tiles x 5 band offsets = 20 accs.
// Band mapping d = 16p + n - m, frag layout, epilogue: validated R5-R16.
// ---------------------------------------------------------------------------
__global__ __launch_bounds__(256)
void corr_gram(const float* __restrict__ x0, const float* __restrict__ x1,
               f16* __restrict__ ws) {
    const int f = blockIdx.x;              // [0, 2048)
    const int unit = (f & 7) * 256 + (f >> 3);
    const int strip = unit & 1;
    const int pair = unit >> 1;            // [0, 1024)
    const int y = pair & 255;
    const int b = pair >> 8;
    const int X0 = strip << 8;             // 0 or 256

    const int t = threadIdx.x;
    const int l = t & 63;
    const int w = t >> 6;
    const int n  = l & 15;
    const int kq = l >> 4;

    __shared__ f16 S[20736];               // SA [256][36] @0, SB [320][36] @9216
    f16* SA = S;
    f16* SB = S + 9216;

    const float* x0r = x0 + (size_t)b * CF * CH + (size_t)y * WF;
    const float* x1r = x1 + (size_t)b * CF * CH + (size_t)y * WF;

    // A staging map: cgA = col-group (lane-major -> 1 KB bursts), quads qbA,qbA+4
    const int cgA = t & 63, qbA = t >> 6;
    // B staging map: units u = t + 256k (k<3, u<640): qB = u/80, cgB = u%80
    int qB[3], cgB[3], colB[3]; bool vB[3], okB[3];
#pragma unroll
    for (int k = 0; k < 3; ++k) {
        const int u = t + 256 * k;
        vB[k] = (u < 640);
        const int uu = vB[k] ? u : 0;
        qB[k] = uu / 80;
        cgB[k] = uu - 80 * qB[k];
        const int col = X0 - 32 + 4 * cgB[k];
        okB[k] = (col >= 0) && (col + 3 < WF);
        colB[k] = okB[k] ? col : 0;
    }

    f32x4 acc[20];
#pragma unroll
    for (int i = 0; i < 20; ++i) acc[i] = (f32x4)0.0f;

    f32x4 AR[8], BR[12], AR2[8], BR2[12];

#define LOADH(h, A_, B_) do { \
    _Pragma("unroll") \
    for (int jq = 0; jq < 2; ++jq) { \
        const int q = qbA + 4 * jq; \
        _Pragma("unroll") \
        for (int i = 0; i < 4; ++i) \
            A_[4*jq+i] = *(const f32x4*)(x0r + (size_t)((h)*32 + 4*q + i) * CH + X0 + 4*cgA); \
    } \
    _Pragma("unroll") \
    for (int k = 0; k < 3; ++k) { \
        _Pragma("unroll") \
        for (int i = 0; i < 4; ++i) \
            B_[4*k+i] = (vB[k] && okB[k]) \
                ? *(const f32x4*)(x1r + (size_t)((h)*32 + 4*qB[k] + i) * CH + colB[k]) \
                : (f32x4)0.0f; \
    } \
} while (0)

#define CVTW(A_, B_) do { \
    _Pragma("unroll") \
    for (int jq = 0; jq < 2; ++jq) { \
        const int q = qbA + 4 * jq; \
        _Pragma("unroll") \
        for (int j2 = 0; j2 < 4; ++j2) { \
            f16x4 v; \
            v[0] = (f16)A_[4*jq+0][j2]; v[1] = (f16)A_[4*jq+1][j2]; \
            v[2] = (f16)A_[4*jq+2][j2]; v[3] = (f16)A_[4*jq+3][j2]; \
            *(f16x4*)&SA[(4*cgA + j2) * APAD + 4*q] = v; \
        } \
    } \
    _Pragma("unroll") \
    for (int k = 0; k < 3; ++k) { \
        if (vB[k]) { \
            _Pragma("unroll") \
            for (int j2 = 0; j2 < 4; ++j2) { \
                f16x4 v; \
                v[0] = (f16)B_[4*k+0][j2]; v[1] = (f16)B_[4*k+1][j2]; \
                v[2] = (f16)B_[4*k+2][j2]; v[3] = (f16)B_[4*k+3][j2]; \
                *(f16x4*)&SB[(4*cgB[k] + j2) * APAD + 4*qB[k]] = v; \
            } \
        } \
    } \
} while (0)

#define COMP() do { \
    f16x8 a0 = *(const f16x8*)&SA[(64*w +  0 + n) * APAD + kq*8]; \
    f16x8 a1 = *(const f16x8*)&SA[(64*w + 16 + n) * APAD + kq*8]; \
    f16x8 a2 = *(const f16x8*)&SA[(64*w + 32 + n) * APAD + kq*8]; \
    f16x8 a3 = *(const f16x8*)&SA[(64*w + 48 + n) * APAD + kq*8]; \
    _Pragma("unroll") \
    for (int jt = 0; jt < 8; ++jt) { \
        const f16x8 bf = *(const f16x8*)&SB[(64*w + 16*jt + n) * APAD + kq*8]; \
        if (jt - 0 >= 0 && jt - 0 < 5) acc[ 0 + jt - 0] = __builtin_amdgcn_mfma_f32_16x16x32_f16(a0, bf, acc[ 0 + jt - 0], 0, 0, 0); \
        if (jt - 1 >= 0 && jt - 1 < 5) acc[ 5 + jt - 1] = __builtin_amdgcn_mfma_f32_16x16x32_f16(a1, bf, acc[ 5 + jt - 1], 0, 0, 0); \
        if (jt - 2 >= 0 && jt - 2 < 5) acc[10 + jt - 2] = __builtin_amdgcn_mfma_f32_16x16x32_f16(a2, bf, acc[10 + jt - 2], 0, 0, 0); \
        if (jt - 3 >= 0 && jt - 3 < 5) acc[15 + jt - 3] = __builtin_amdgcn_mfma_f32_16x16x32_f16(a3, bf, acc[15 + jt - 3], 0, 0, 0); \
    } \
} while (0)

    LOADH(0, AR, BR);
    CVTW(AR, BR);
    __syncthreads();                       // half 0 staged
    LOADH(1, AR2, BR2);                    // prefetch half 1 (T14)
    COMP();                                // half 0
    __syncthreads();
    CVTW(AR2, BR2);
    __syncthreads();                       // half 1 staged
    COMP();                                // half 1
    __syncthreads();                       // LDS free for epilogue

#undef COMP
#undef CVTW
#undef LOADH

    // ---- epilogue: scatter band to LDS [256][72], nt coalesced stores ----
    f16* eb = S;
#pragma unroll
    for (int xt = 0; xt < 4; ++xt) {
#pragma unroll
        for (int p = 0; p < 5; ++p) {
#pragma unroll
            for (int q = 0; q < 4; ++q) {
                const int m = kq * 4 + q;
                const int xl = 64 * w + 16 * xt + m;
                const int d = 16 * p + n - m;
                if ((unsigned)d < (unsigned)NDTOT)
                    eb[xl * DP + d] = (f16)acc[xt * 5 + p][q];
            }
        }
    }
    // zero pad d=65..71: thread t owns col t's 7 pad entries
#pragma unroll
    for (int dd = 0; dd < 7; ++dd) eb[t * DP + NDTOT + dd] = (f16)0.f;
    __syncthreads();

    // nt coalesced store: 256*72 f16 = 36864 B = 2304 x 16B chunks
    u32x4* dst = (u32x4*)(ws + ((size_t)(b * HF + y) * WF + X0) * DP);
    const u32x4* src = (const u32x4*)eb;
#pragma unroll
    for (int i = 0; i < 9; ++i)
        __builtin_nontemporal_store(src[t + 256 * i], &dst[t + 256 * i]);
}

// ---------------------------------------------------------------------------
// k2: 3x3 box-sum over ws + scale. nt loads (ws read once) + nt stores
// (out never re-read) keep the L3 for the x0/x1 inputs.
// grid (16 x-tiles of 32, 32 y-tiles of 8, b); 256 thr.
// ---------------------------------------------------------------------------
__global__ __launch_bounds__(256)
void corr_box(const f16* __restrict__ ws, float* __restrict__ out) {
    const int xt = blockIdx.x;
    const int yt = blockIdx.y;
    const int b = blockIdx.z;
    const int t = threadIdx.x;
    const int x0b = xt * 32, y0 = yt * 8;

    __shared__ f16 S[10 * 34][DP];     // 48.96 KB

    for (int u = 0; u < 10; ++u) {
        const int yy = y0 - 1 + u;
        const bool yok = (unsigned)yy < (unsigned)HF;
        const f16* src = ws + ((size_t)(b * HF + yy) * WF + (x0b - 1)) * DP;
#pragma unroll
        for (int sub = 0; sub < 2; ++sub) {
            const int idx = sub * 256 + t;
            if (idx < 306) {
                const int v = idx / 9, dg = idx - v * 9;
                const int xx = x0b - 1 + v;
                f16x8 val;
#pragma unroll
                for (int jj = 0; jj < 8; ++jj) val[jj] = (f16)0.f;
                if (yok && (unsigned)xx < (unsigned)WF)
                    val = __builtin_nontemporal_load((const f16x8*)(src + (size_t)v * DP + dg * 8));
                *(f16x8*)&S[u * 34 + v][dg * 8] = val;
            }
        }
    }
    __syncthreads();

    const int ly = t >> 5, lx = t & 31;
    const int yg = y0 + ly, xg = x0b + lx;
    float* o0 = out + (size_t)b * NDTOT * WH + (size_t)yg * WF + xg;

#pragma unroll 1
    for (int dg = 0; dg < 9; ++dg) {
        f16x8 s;
#pragma unroll
        for (int jj = 0; jj < 8; ++jj) s[jj] = (f16)0.f;
#pragma unroll
        for (int du = 0; du < 3; ++du)
#pragma unroll
            for (int dv = 0; dv < 3; ++dv)
                s += *(const f16x8*)&S[(ly + du) * 34 + (lx + dv)][dg * 8];
#pragma unroll
        for (int jj = 0; jj < 8; ++jj) {
            const int d = dg * 8 + jj;
            if (d < NDTOT)
                __builtin_nontemporal_store((float)s[jj] * INV, &o0[(size_t)d * WH]);
        }
    }
}

// ---------------------------------------------------------------------------
// Emergency fallback (tiny ws): direct computation, slow but correct.
// ---------------------------------------------------------------------------
__global__ void corr_naive(const float* __restrict__ x0, const float* __restrict__ x1,
                           float* __restrict__ out) {
    const size_t total = (size_t)4 * NDTOT * WH;
    size_t idx = (size_t)blockIdx.x * blockDim.x + threadIdx.x;
    if (idx >= total) return;
    const int j = (int)(idx % WF);
    const int i = (int)((idx / WF) % HF);
    const int d = (int)((idx / WH) % NDTOT);
    const int b = (int)(idx / ((size_t)NDTOT * WH));
    const int disp = d - 32;
    float s = 0.f;
    for (int u = i - 1; u <= i + 1; ++u) {
        if (u < 0 || u >= HF) continue;
        for (int v = j - 1; v <= j + 1; ++v) {
            if (v < 0 || v >= WF) continue;
            const int v1c = v + disp;
            if (v1c < 0 || v1c >= WF) continue;
            const float* p0 = x0 + (size_t)b * CF * CH + (size_t)u * WF + v;
            const float* p1 = x1 + (size_t)b * CF * CH + (size_t)u * WF + v1c;
            for (int c = 0; c < CF; ++c)
                s += p0[(size_t)c * CH] * p1[(size_t)c * CH];
        }
    }
    out[idx] = s * INV;
}

// ---------------------------------------------------------------------------
extern "C" void kernel_launch(void* const* d_in, const int* in_sizes, int n_in,
                              void* d_out, int out_size, void* d_ws, size_t ws_size,
                              hipStream_t stream) {
    const float* x0 = (const float*)d_in[0];
    const float* x1 = (const float*)d_in[1];
    float* out = (float*)d_out;

    const size_t wsNeed = (size_t)4 * HF * WF * DP * sizeof(f16);  // 75.5 MB

    if (ws_size >= wsNeed) {
        f16* ws = (f16*)d_ws;
        corr_gram<<<dim3(2048), dim3(256), 0, stream>>>(x0, x1, ws);
        corr_box<<<dim3(16, 32, 4), dim3(256), 0, stream>>>(ws, out);
    } else {
        const size_t total = (size_t)4 * NDTOT * WH;
        const int blocks = (int)((total + 255) / 256);
        corr_naive<<<dim3(blocks), dim3(256), 0, stream>>>(x0, x1, out);
    }
}